// Round 12
// baseline (138.405 us; speedup 1.0000x reference)
//
#include <hip/hip_runtime.h>
#include <stdint.h>

#define NB 1024
#define NK 4096
#define NO 4096
#define DELTA 4e-7

typedef __attribute__((ext_vector_type(8))) short s16x8;
typedef __attribute__((ext_vector_type(4))) float f32x4;
typedef __attribute__((ext_vector_type(4))) int i32x4;
typedef __attribute__((ext_vector_type(16))) char c8x16;

static __device__ __forceinline__ unsigned short f2bf_rne(float x) {
  union { float f; unsigned u; } c; c.f = x;
  unsigned r = (c.u + 0x7FFFu + ((c.u >> 16) & 1u)) >> 16;
  return (unsigned short)r;
}
static __device__ __forceinline__ float bf2f(unsigned short h) {
  union { float f; unsigned u; } c; c.u = ((unsigned)h) << 16;
  return c.f;
}

// ---- cvt kernels: f32 -> i8 FRAGMENT-MAJOR layout --------------------------
// Each 16B chunk is exactly one lane's MFMA fragment slice; a wave's fragment
// load is chunk_base + lane*16 -> one coalesced global_load_dwordx4, straight
// to registers. No LDS anywhere in the GEMM.
// A chunk iA = (bm*2+wm)*16384 + kt*256 + mi*64 + lane
//   row = bm*128+wm*64+mi*16+(lane&15), col = kt*64+(lane>>4)*16
__global__ void cvtA8f_kernel(const float* __restrict__ A, signed char* __restrict__ A8f) {
  const int n = 262144;
  for (int i = blockIdx.x * blockDim.x + threadIdx.x; i < n; i += gridDim.x * blockDim.x) {
    const int lane = i & 63, mi = (i >> 6) & 3, kt = (i >> 8) & 63, pw = i >> 14;
    const int row = (pw >> 1) * 128 + (pw & 1) * 64 + mi * 16 + (lane & 15);
    const int col = kt * 64 + (lane >> 4) * 16;
    const float* src = A + ((size_t)row << 12) + col;
    c8x16 v;
#pragma unroll
    for (int j = 0; j < 4; ++j) {
      float4 f = *(const float4*)(src + j * 4);
      v[j * 4 + 0] = (char)(int)f.x; v[j * 4 + 1] = (char)(int)f.y;
      v[j * 4 + 2] = (char)(int)f.z; v[j * 4 + 3] = (char)(int)f.w;
    }
    *(c8x16*)(A8f + (size_t)i * 16) = v;
  }
}

// W' = round(W*2^16) = q1*128 + q0 (exact). Chunk
// iW = (bn*2+wn)*16384 + kt*256 + lv*128 + ni*64 + lane
//   row = bn*64+wn*32+ni*16+(lane&15), col = kt*64+(lane>>4)*16
__global__ void cvtW8f_kernel(const float* __restrict__ W, signed char* __restrict__ W8f) {
  const int n = 1048576;
  for (int j = blockIdx.x * blockDim.x + threadIdx.x; j < n; j += gridDim.x * blockDim.x) {
    const int lane = j & 63, ni = (j >> 6) & 1, kt = (j >> 7) & 63, pw = j >> 13;
    const int row = (pw >> 1) * 64 + (pw & 1) * 32 + ni * 16 + (lane & 15);
    const int col = kt * 64 + (lane >> 4) * 16;
    const float* src = W + ((size_t)row << 12) + col;
    c8x16 v1, v0;
#pragma unroll
    for (int t = 0; t < 16; ++t) {
      const int qi = (int)rintf(src[t] * 65536.0f);
      const int q1 = (qi + 64) >> 7;
      const int q0 = qi - (q1 << 7);
      v1[t] = (char)q1; v0[t] = (char)q0;
    }
    const size_t base = ((size_t)pw << 14) + kt * 256 + ni * 64 + lane; // lv=0
    *(c8x16*)(W8f + base * 16) = v1;
    *(c8x16*)(W8f + (base + 128) * 16) = v0;   // lv stride = 128 chunks
  }
}

// ---- register-resident fragment pipeline (no LDS, no barriers) ------------
struct Frag { i32x4 a0, a1, a2, a3, h0, h1, l0, l1; };

static __device__ __forceinline__ void loadF(Frag& f, const char* pA, const char* pW, int kt) {
  const char* qa = pA + ((size_t)kt << 12);
  f.a0 = *(const i32x4*)(qa);
  f.a1 = *(const i32x4*)(qa + 1024);
  f.a2 = *(const i32x4*)(qa + 2048);
  f.a3 = *(const i32x4*)(qa + 3072);
  const char* qw = pW + ((size_t)kt << 12);
  f.h0 = *(const i32x4*)(qw);
  f.h1 = *(const i32x4*)(qw + 1024);
  f.l0 = *(const i32x4*)(qw + 2048);
  f.l1 = *(const i32x4*)(qw + 3072);
}

static __device__ __forceinline__ void mfmaF(const Frag& f,
                                             i32x4 (&acc1)[4][2], i32x4 (&acc0)[4][2]) {
  const i32x4 af[4] = {f.a0, f.a1, f.a2, f.a3};
  const i32x4 b1[2] = {f.h0, f.h1};
  const i32x4 b0[2] = {f.l0, f.l1};
#pragma unroll
  for (int mi = 0; mi < 4; ++mi)
#pragma unroll
    for (int ni = 0; ni < 2; ++ni) {
      acc1[mi][ni] = __builtin_amdgcn_mfma_i32_16x16x64_i8(af[mi], b1[ni], acc1[mi][ni], 0, 0, 0);
      acc0[mi][ni] = __builtin_amdgcn_mfma_i32_16x16x64_i8(af[mi], b0[ni], acc0[mi][ni], 0, 0, 0);
    }
}

// 128x64 tile, 4 waves (64x32 each), fragments streamed global->reg, 512 blocks
__global__ __launch_bounds__(256, 2) void snn_gemm_reg(
    const signed char* __restrict__ A8f, const signed char* __restrict__ W8f,
    const float* __restrict__ prev, const float* __restrict__ Wf,
    const float* __restrict__ own_mems, const float* __restrict__ own_spikes,
    const float* __restrict__ tau, float* __restrict__ out) {
  const int tid = threadIdx.x;
  const int lane = tid & 63;
  const int wave = tid >> 6;
  const int wm = wave >> 1, wn = wave & 1;

  // XCD-aware bijective swizzle: 512 blocks, 64/XCD; W panels XCD-local
  const int bid = blockIdx.x;
  const int s = (bid & 7) * 64 + (bid >> 3);
  const int bm = s & 7, bn = s >> 3;

  const char* pA = (const char*)A8f + ((size_t)(bm * 2 + wm) << 18) + lane * 16;
  const char* pW = (const char*)W8f + ((size_t)(bn * 2 + wn) << 18) + lane * 16;

  const int fr = lane & 15;
  const int fq = lane >> 4;

  i32x4 acc1[4][2], acc0[4][2];
#pragma unroll
  for (int i = 0; i < 4; ++i)
#pragma unroll
    for (int j = 0; j < 2; ++j) { acc1[i][j] = (i32x4){0, 0, 0, 0};
                                  acc0[i][j] = (i32x4){0, 0, 0, 0}; }

  // 3-deep register rotation: at step t, fA=kt t, fB=t+1; load t+2 into fC.
  Frag fA, fB, fC;
  loadF(fA, pA, pW, 0);
  loadF(fB, pA, pW, 1);
#pragma unroll 1
  for (int m = 0; m < 21; ++m) {
    const int t = 3 * m;
    loadF(fC, pA, pW, (t + 2) & 63); mfmaF(fA, acc1, acc0);
    loadF(fA, pA, pW, (t + 3) & 63); mfmaF(fB, acc1, acc0);
    loadF(fB, pA, pW, (t + 4) & 63); mfmaF(fC, acc1, acc0);
  }
  mfmaF(fA, acc1, acc0);  // step 63 (loaded in the m=20 iteration)

  // ---- epilogue: dot = (acc1*128 + acc0) * 2^-16 (exact) ----
  const float inv = 1.0f / 65536.0f;
  unsigned fm = 0u;
#pragma unroll
  for (int ni = 0; ni < 2; ++ni) {
    const int gc = bn * 64 + wn * 32 + ni * 16 + fr;
    const float alpha = 1.0f / (1.0f + expf(-tau[gc]));
#pragma unroll
    for (int mi = 0; mi < 4; ++mi) {
#pragma unroll
      for (int j = 0; j < 4; ++j) {
        const int gr = bm * 128 + wm * 64 + mi * 16 + fq * 4 + j;
        const size_t idx = (size_t)gr * NO + gc;
        const int comb = (acc1[mi][ni][j] << 7) + acc0[mi][ni][j];
        const float dec = own_mems[idx] * alpha * (1.0f - own_spikes[idx]);
        const float mem = (float)comb * inv + dec;
        out[idx] = (mem < 0.3f) ? mem : 0.0f;
        out[(size_t)NB * NO + idx] = (mem > 0.3f) ? 1.0f : 0.0f;
        if (fabsf(mem - 0.3f) < 1e-3f)
          fm |= 1u << ((mi * 2 + ni) * 4 + j);
      }
    }
  }

  // ---- inline f64 fixup (razor-edge decisions biased by DELTA) ----
#pragma unroll 1
  for (int r = 0; r < 32; ++r) {
    unsigned long long m = __ballot((fm >> r) & 1u);
    if (m == 0ull) continue;
    const int mi = r >> 3, ni = (r >> 2) & 1, j = r & 3;
    const int gr_r = bm * 128 + wm * 64 + mi * 16 + fq * 4 + j;
    const int gc_r = bn * 64 + wn * 32 + ni * 16 + fr;
    while (m) {
      const int l = (int)__ffsll(m) - 1;
      m &= m - 1ull;
      const int gr = __shfl(gr_r, l, 64);
      const int gc = __shfl(gc_r, l, 64);
      const float* ap = prev + (size_t)gr * NK;
      const float* wp = Wf + (size_t)gc * NK;
      double s0 = 0.0, s1 = 0.0;
#pragma unroll 2
      for (int jj = 0; jj < 64; jj += 2) {
        s0 += (double)ap[lane + jj * 64]       * (double)wp[lane + jj * 64];
        s1 += (double)ap[lane + (jj + 1) * 64] * (double)wp[lane + (jj + 1) * 64];
      }
      double sum = s0 + s1;
#pragma unroll
      for (int off = 1; off < 64; off <<= 1) sum += __shfl_xor(sum, off, 64);
      if (lane == 0) {
        const size_t idx = (size_t)gr * NO + gc;
        const double alpha = 1.0 / (1.0 + exp(-(double)tau[gc]));
        const double dec = (double)own_mems[idx] * alpha * (1.0 - (double)own_spikes[idx]);
        const double mv = dec + sum;
        const double T = 0.3 + DELTA;
        out[idx] = (mv < T) ? (float)mv : 0.0f;
        out[(size_t)NB * NO + idx] = (mv > T) ? 1.0f : 0.0f;
      }
    }
  }
}

// ---------------- fallback: round-4 fused kernel (known-PASS) --------------
__global__ __launch_bounds__(256) void snn_fused(
    const float* __restrict__ prev, const float* __restrict__ Wf,
    const float* __restrict__ own_mems, const float* __restrict__ own_spikes,
    const float* __restrict__ tau, float* __restrict__ out) {
  __shared__ __align__(16) unsigned short sA[128 * 32];
  __shared__ __align__(16) unsigned short sH[128 * 32];
  __shared__ __align__(16) unsigned short sL[128 * 32];
  const int tid = threadIdx.x;
  const int lane = tid & 63;
  const int wave = tid >> 6;
  const int wm = wave >> 1, wn = wave & 1;
  const int bn = blockIdx.x, bm = blockIdx.y;
  const int srow = tid >> 1;
  const int scol = (tid & 1) * 16;
  const float* gA = prev + (size_t)(bm * 128 + srow) * NK + scol;
  const float* gW = Wf + (size_t)(bn * 128 + srow) * NK + scol;
  const int sb = srow * 32 + scol;
  f32x4 acc[4][4];
#pragma unroll
  for (int i = 0; i < 4; ++i)
#pragma unroll
    for (int j = 0; j < 4; ++j) acc[i][j] = (f32x4){0.f, 0.f, 0.f, 0.f};
  const int fr = lane & 15;
  const int fq = lane >> 4;
  const int fk = fq * 8;
  for (int kt = 0; kt < NK / 32; ++kt) {
    const int ko = kt * 32;
    float av[16], wv[16];
    *(float4*)&av[0]  = *(const float4*)(gA + ko);
    *(float4*)&av[4]  = *(const float4*)(gA + ko + 4);
    *(float4*)&av[8]  = *(const float4*)(gA + ko + 8);
    *(float4*)&av[12] = *(const float4*)(gA + ko + 12);
    *(float4*)&wv[0]  = *(const float4*)(gW + ko);
    *(float4*)&wv[4]  = *(const float4*)(gW + ko + 4);
    *(float4*)&wv[8]  = *(const float4*)(gW + ko + 8);
    *(float4*)&wv[12] = *(const float4*)(gW + ko + 12);
    s16x8 va0, va1, vh0, vh1, vl0, vl1;
#pragma unroll
    for (int j = 0; j < 8; ++j) {
      va0[j] = (short)f2bf_rne(av[j]);
      va1[j] = (short)f2bf_rne(av[j + 8]);
      const unsigned short h0 = f2bf_rne(wv[j]);
      vh0[j] = (short)h0;
      vl0[j] = (short)f2bf_rne(wv[j] - bf2f(h0));
      const unsigned short h1 = f2bf_rne(wv[j + 8]);
      vh1[j] = (short)h1;
      vl1[j] = (short)f2bf_rne(wv[j + 8] - bf2f(h1));
    }
    __syncthreads();
    *(s16x8*)&sA[sb] = va0; *(s16x8*)&sA[sb + 8] = va1;
    *(s16x8*)&sH[sb] = vh0; *(s16x8*)&sH[sb + 8] = vh1;
    *(s16x8*)&sL[sb] = vl0; *(s16x8*)&sL[sb + 8] = vl1;
    __syncthreads();
    s16x8 af[4], bh[4], bl[4];
#pragma unroll
    for (int mi = 0; mi < 4; ++mi)
      af[mi] = *(const s16x8*)&sA[(wm * 64 + mi * 16 + fr) * 32 + fk];
#pragma unroll
    for (int ni = 0; ni < 4; ++ni) {
      bh[ni] = *(const s16x8*)&sH[(wn * 64 + ni * 16 + fr) * 32 + fk];
      bl[ni] = *(const s16x8*)&sL[(wn * 64 + ni * 16 + fr) * 32 + fk];
    }
#pragma unroll
    for (int mi = 0; mi < 4; ++mi)
#pragma unroll
      for (int ni = 0; ni < 4; ++ni) {
        acc[mi][ni] = __builtin_amdgcn_mfma_f32_16x16x32_bf16(af[mi], bh[ni], acc[mi][ni], 0, 0, 0);
        acc[mi][ni] = __builtin_amdgcn_mfma_f32_16x16x32_bf16(af[mi], bl[ni], acc[mi][ni], 0, 0, 0);
      }
  }
  unsigned long long fm = 0ull;
#pragma unroll
  for (int ni = 0; ni < 4; ++ni) {
    const int gc = bn * 128 + wn * 64 + ni * 16 + fr;
    const float alpha = 1.0f / (1.0f + expf(-tau[gc]));
#pragma unroll
    for (int mi = 0; mi < 4; ++mi) {
#pragma unroll
      for (int j = 0; j < 4; ++j) {
        const int gr = bm * 128 + wm * 64 + mi * 16 + fq * 4 + j;
        const size_t idx = (size_t)gr * NO + gc;
        const float dec = own_mems[idx] * alpha * (1.0f - own_spikes[idx]);
        const float mem = acc[mi][ni][j] + dec;
        out[idx] = (mem < 0.3f) ? mem : 0.0f;
        out[(size_t)NB * NO + idx] = (mem > 0.3f) ? 1.0f : 0.0f;
        if (fabsf(mem - 0.3f) < 1e-3f)
          fm |= 1ull << (mi * 16 + ni * 4 + j);
      }
    }
  }
#pragma unroll 1
  for (int r = 0; r < 64; ++r) {
    unsigned long long m = __ballot((fm >> r) & 1ull);
    if (m == 0ull) continue;
    const int mi = r >> 4, ni = (r >> 2) & 3, j = r & 3;
    const int gr_r = bm * 128 + wm * 64 + mi * 16 + fq * 4 + j;
    const int gc_r = bn * 128 + wn * 64 + ni * 16 + fr;
    while (m) {
      const int l = (int)__ffsll(m) - 1;
      m &= m - 1ull;
      const int gr = __shfl(gr_r, l, 64);
      const int gc = __shfl(gc_r, l, 64);
      const float* ap = prev + (size_t)gr * NK;
      const float* wp = Wf + (size_t)gc * NK;
      double s0 = 0.0, s1 = 0.0;
#pragma unroll 2
      for (int jj = 0; jj < 64; jj += 2) {
        s0 += (double)ap[lane + jj * 64]       * (double)wp[lane + jj * 64];
        s1 += (double)ap[lane + (jj + 1) * 64] * (double)wp[lane + (jj + 1) * 64];
      }
      double sum = s0 + s1;
#pragma unroll
      for (int off = 1; off < 64; off <<= 1) sum += __shfl_xor(sum, off, 64);
      if (lane == 0) {
        const size_t idx = (size_t)gr * NO + gc;
        const double alpha = 1.0 / (1.0 + exp(-(double)tau[gc]));
        const double dec = (double)own_mems[idx] * alpha * (1.0 - (double)own_spikes[idx]);
        const double mv = dec + sum;
        const double T = 0.3 + DELTA;
        out[idx] = (mv < T) ? (float)mv : 0.0f;
        out[(size_t)NB * NO + idx] = (mv > T) ? 1.0f : 0.0f;
      }
    }
  }
}

extern "C" void kernel_launch(void* const* d_in, const int* in_sizes, int n_in,
                              void* d_out, int out_size, void* d_ws, size_t ws_size,
                              hipStream_t stream) {
  const float* prev_spikes = (const float*)d_in[0];
  const float* own_mems    = (const float*)d_in[1];
  const float* own_spikes  = (const float*)d_in[2];
  const float* W           = (const float*)d_in[3];
  const float* tau         = (const float*)d_in[4];
  float* out = (float*)d_out;

  const size_t aBytes = (size_t)NB * NK;       // 4 MB i8 frag-blob
  const size_t wBytes = (size_t)NO * NK * 2;   // 32 MB i8 frag-blob (q1|q0)
  if (ws_size >= aBytes + wBytes) {
    char* p = (char*)d_ws;
    signed char* A8f = (signed char*)p;
    signed char* W8f = (signed char*)(p + aBytes);
    cvtA8f_kernel<<<1024, 256, 0, stream>>>(prev_spikes, A8f);
    cvtW8f_kernel<<<2048, 256, 0, stream>>>(W, W8f);
    snn_gemm_reg<<<512, 256, 0, stream>>>(A8f, W8f, prev_spikes, W,
                                          own_mems, own_spikes, tau, out);
  } else {
    snn_fused<<<dim3(NO / 128, NB / 128), 256, 0, stream>>>(
        prev_spikes, W, own_mems, own_spikes, tau, out);
  }
}

// Round 13
// 104.941 us; speedup vs baseline: 1.3189x; 1.3189x over previous
//
#include <hip/hip_runtime.h>
#include <stdint.h>

#define NB 1024
#define NK 4096
#define NO 4096
#define DELTA 4e-7

typedef __attribute__((ext_vector_type(8))) short s16x8;
typedef __attribute__((ext_vector_type(4))) float f32x4;
typedef __attribute__((ext_vector_type(4))) int i32x4;
typedef __attribute__((ext_vector_type(16))) char c8x16;

static __device__ __forceinline__ unsigned short f2bf_rne(float x) {
  union { float f; unsigned u; } c; c.f = x;
  unsigned r = (c.u + 0x7FFFu + ((c.u >> 16) & 1u)) >> 16;
  return (unsigned short)r;
}
static __device__ __forceinline__ float bf2f(unsigned short h) {
  union { float f; unsigned u; } c; c.u = ((unsigned)h) << 16;
  return c.f;
}

// async global->LDS DMA, 16B/lane. LDS dest = wave-uniform base + lane*16.
static __device__ __forceinline__ void gload16(const void* g, void* l) {
  __builtin_amdgcn_global_load_lds((const __attribute__((address_space(1))) void*)g,
                                   (__attribute__((address_space(3))) void*)l, 16, 0, 0);
}

// ---- convert kernels: f32 -> i8 TILE-BLOB layout (R11, proven) ------------
__global__ void cvtA8t_kernel(const float* __restrict__ A, signed char* __restrict__ A8t) {
  const int n = NB * NK / 16;
  for (int i = blockIdx.x * blockDim.x + threadIdx.x; i < n; i += gridDim.x * blockDim.x) {
    const int bm = i >> 15, rem = i & 32767;
    const int kt = rem >> 9, rem2 = rem & 511;
    const int l = rem2 >> 3, c = rem2 & 7;
    const int row = bm * 128 + 2 * l + (c >> 2);
    const int col = kt * 64 + (c & 3) * 16;
    const float* src = A + ((size_t)row << 12) + col;
    c8x16 v;
#pragma unroll
    for (int j = 0; j < 4; ++j) {
      float4 f = *(const float4*)(src + j * 4);
      v[j * 4 + 0] = (char)(int)f.x; v[j * 4 + 1] = (char)(int)f.y;
      v[j * 4 + 2] = (char)(int)f.z; v[j * 4 + 3] = (char)(int)f.w;
    }
    const size_t dst = ((size_t)(bm * 64 + kt) << 13) + l * 128 + ((c ^ (l & 7)) << 4);
    *(c8x16*)(A8t + dst) = v;
  }
}

__global__ void cvtW8t_kernel(const float* __restrict__ W, signed char* __restrict__ W8t) {
  const int n = NO * NK / 16;
  for (int i = blockIdx.x * blockDim.x + threadIdx.x; i < n; i += gridDim.x * blockDim.x) {
    const int bn = i >> 14, rem = i & 16383;
    const int kt = rem >> 8, rem2 = rem & 255;
    const int l = rem2 >> 3, c = rem2 & 7;
    const int row = bn * 64 + 2 * l + (c >> 2);
    const int col = kt * 64 + (c & 3) * 16;
    const float* src = W + ((size_t)row << 12) + col;
    c8x16 v1, v0;
#pragma unroll
    for (int j = 0; j < 16; ++j) {
      const int qi = (int)rintf(src[j] * 65536.0f);
      const int q1 = (qi + 64) >> 7;
      const int q0 = qi - (q1 << 7);
      v1[j] = (char)q1; v0[j] = (char)q0;
    }
    const size_t dst = ((size_t)(bn * 64 + kt) << 13) + l * 128 + ((c ^ (l & 7)) << 4);
    *(c8x16*)(W8t + dst) = v1;
    *(c8x16*)(W8t + dst + 4096) = v0;
  }
}

static __device__ __forceinline__ void frag_read2(
    const char* rb, const int (&offA)[2], const int (&offB)[2],
    i32x4 (&af)[2], i32x4 (&b1)[2], i32x4 (&b0)[2]) {
#pragma unroll
  for (int mi = 0; mi < 2; ++mi) af[mi] = *(const i32x4*)(rb + offA[mi]);
#pragma unroll
  for (int ni = 0; ni < 2; ++ni) {
    b1[ni] = *(const i32x4*)(rb + 8192 + offB[ni]);
    b0[ni] = *(const i32x4*)(rb + 12288 + offB[ni]);
  }
}

static __device__ __forceinline__ void mfma8(
    const i32x4 (&af)[2], const i32x4 (&b1)[2], const i32x4 (&b0)[2],
    i32x4 (&acc1)[2][2], i32x4 (&acc0)[2][2]) {
  __builtin_amdgcn_s_setprio(1);
#pragma unroll
  for (int mi = 0; mi < 2; ++mi)
#pragma unroll
    for (int ni = 0; ni < 2; ++ni) {
      acc1[mi][ni] = __builtin_amdgcn_mfma_i32_16x16x64_i8(af[mi], b1[ni], acc1[mi][ni], 0, 0, 0);
      acc0[mi][ni] = __builtin_amdgcn_mfma_i32_16x16x64_i8(af[mi], b0[ni], acc0[mi][ni], 0, 0, 0);
    }
  __builtin_amdgcn_s_setprio(0);
}

// ---- main GEMM: 128x64 tile, 8 waves (4Mx2N, 32x32/wave), 16 waves/CU -----
__global__ __launch_bounds__(512, 4) void snn_gemm_w8(
    const signed char* __restrict__ A8t, const signed char* __restrict__ W8t,
    const float* __restrict__ prev, const float* __restrict__ Wf,
    const float* __restrict__ own_mems, const float* __restrict__ own_spikes,
    const float* __restrict__ tau, float* __restrict__ out) {
  __shared__ __align__(16) char ring[3][16384];   // slot = [A 8KB | q1 4KB | q0 4KB]

  const int tid = threadIdx.x;
  const int lane = tid & 63;
  const int wave = tid >> 6;           // 0..7
  const int wm = wave >> 1, wn = wave & 1;

  const int bid = blockIdx.x;
  const int s = (bid & 7) * 64 + (bid >> 3);
  const int bm = s & 7, bn = s >> 3;

  const int woff = wave << 10;         // wave-uniform LDS sub-base (1KB/wave)
  const char* pA = (const char*)A8t + ((size_t)(bm * 64) << 13) + tid * 16;
  const char* pW = (const char*)W8t + ((size_t)(bn * 64) << 13) + tid * 16;

  const int fr = lane & 15;
  const int fq = lane >> 4;

  int offA[2], offB[2];
#pragma unroll
  for (int mi = 0; mi < 2; ++mi) {
    const int r = wm * 32 + mi * 16 + fr, l = r >> 1;
    offA[mi] = l * 128 + ((((r & 1) * 4 + fq) ^ (l & 7)) * 16);
  }
#pragma unroll
  for (int ni = 0; ni < 2; ++ni) {
    const int r = wn * 32 + ni * 16 + fr, l = r >> 1;
    offB[ni] = l * 128 + ((((r & 1) * 4 + fq) ^ (l & 7)) * 16);
  }

  i32x4 acc1[2][2], acc0[2][2];
#pragma unroll
  for (int i = 0; i < 2; ++i)
#pragma unroll
    for (int j = 0; j < 2; ++j) { acc1[i][j] = (i32x4){0, 0, 0, 0};
                                  acc0[i][j] = (i32x4){0, 0, 0, 0}; }

  i32x4 afA[2], b1A[2], b0A[2], afB[2], b1B[2], b0B[2];

#define STAGE(slot, kt) { const size_t _ko = ((size_t)((kt) & 63) << 13);  \
    gload16(pA + _ko, ring[slot] + woff);                                  \
    gload16(pW + _ko, ring[slot] + 8192 + woff); }

#define SYNC asm volatile("s_waitcnt vmcnt(2) lgkmcnt(0)" ::: "memory"); \
    __builtin_amdgcn_s_barrier();

#define STEP(rd, st, kt, AFU, B1U, B0U, AFN, B1N, B0N)               \
    frag_read2(ring[rd], offA, offB, AFN, B1N, B0N);                 \
    STAGE(st, kt)                                                    \
    mfma8(AFU, B1U, B0U, acc1, acc0);                                \
    SYNC

  // prologue: stage tiles 0,1,2; tiles 0,1 landed; frags(0) -> A regs
  STAGE(0, 0) STAGE(1, 1) STAGE(2, 2)
  asm volatile("s_waitcnt vmcnt(2)" ::: "memory");
  __builtin_amdgcn_s_barrier();
  frag_read2(ring[0], offA, offB, afA, b1A, b0A);
  asm volatile("s_waitcnt lgkmcnt(0)" ::: "memory");
  __builtin_amdgcn_s_barrier();   // all waves' slot-0 reads done before t=0 stage

#pragma unroll 1
  for (int m = 0; m < 10; ++m) {
    const int t = 6 * m;
    STEP(1, 0, t + 3, afA, b1A, b0A, afB, b1B, b0B)
    STEP(2, 1, t + 4, afB, b1B, b0B, afA, b1A, b0A)
    STEP(0, 2, t + 5, afA, b1A, b0A, afB, b1B, b0B)
    STEP(1, 0, t + 6, afB, b1B, b0B, afA, b1A, b0A)
    STEP(2, 1, t + 7, afA, b1A, b0A, afB, b1B, b0B)
    STEP(0, 2, t + 8, afB, b1B, b0B, afA, b1A, b0A)
  }
  STEP(1, 0, 63, afA, b1A, b0A, afB, b1B, b0B)
  STEP(2, 1, 64, afB, b1B, b0B, afA, b1A, b0A)
  STEP(0, 2, 65, afA, b1A, b0A, afB, b1B, b0B)
  mfma8(afB, b1B, b0B, acc1, acc0);   // step 63
#undef STEP
#undef SYNC
#undef STAGE

  // ---- epilogue: dot = (acc1*128 + acc0) * 2^-16 (exact) ----
  const float inv = 1.0f / 65536.0f;
  unsigned fm = 0u;
#pragma unroll
  for (int ni = 0; ni < 2; ++ni) {
    const int gc = bn * 64 + wn * 32 + ni * 16 + fr;
    const float alpha = 1.0f / (1.0f + expf(-tau[gc]));
#pragma unroll
    for (int mi = 0; mi < 2; ++mi) {
#pragma unroll
      for (int j = 0; j < 4; ++j) {
        const int gr = bm * 128 + wm * 32 + mi * 16 + fq * 4 + j;
        const size_t idx = (size_t)gr * NO + gc;
        const int comb = (acc1[mi][ni][j] << 7) + acc0[mi][ni][j];
        const float dec = own_mems[idx] * alpha * (1.0f - own_spikes[idx]);
        const float mem = (float)comb * inv + dec;
        out[idx] = (mem < 0.3f) ? mem : 0.0f;
        out[(size_t)NB * NO + idx] = (mem > 0.3f) ? 1.0f : 0.0f;
        if (fabsf(mem - 0.3f) < 1e-3f)
          fm |= 1u << ((mi * 2 + ni) * 4 + j);
      }
    }
  }

  // ---- inline f64 fixup (razor-edge decisions biased by DELTA) ----
#pragma unroll 1
  for (int r = 0; r < 16; ++r) {
    unsigned long long m = __ballot((fm >> r) & 1u);
    if (m == 0ull) continue;
    const int mi = r >> 3, ni = (r >> 2) & 1, j = r & 3;
    const int gr_r = bm * 128 + wm * 32 + mi * 16 + fq * 4 + j;
    const int gc_r = bn * 64 + wn * 32 + ni * 16 + fr;
    while (m) {
      const int l = (int)__ffsll(m) - 1;
      m &= m - 1ull;
      const int gr = __shfl(gr_r, l, 64);
      const int gc = __shfl(gc_r, l, 64);
      const float* ap = prev + (size_t)gr * NK;
      const float* wp = Wf + (size_t)gc * NK;
      double s0 = 0.0, s1 = 0.0;
#pragma unroll 2
      for (int jj = 0; jj < 64; jj += 2) {
        s0 += (double)ap[lane + jj * 64]       * (double)wp[lane + jj * 64];
        s1 += (double)ap[lane + (jj + 1) * 64] * (double)wp[lane + (jj + 1) * 64];
      }
      double sum = s0 + s1;
#pragma unroll
      for (int off = 1; off < 64; off <<= 1) sum += __shfl_xor(sum, off, 64);
      if (lane == 0) {
        const size_t idx = (size_t)gr * NO + gc;
        const double alpha = 1.0 / (1.0 + exp(-(double)tau[gc]));
        const double dec = (double)own_mems[idx] * alpha * (1.0 - (double)own_spikes[idx]);
        const double mv = dec + sum;
        const double T = 0.3 + DELTA;
        out[idx] = (mv < T) ? (float)mv : 0.0f;
        out[(size_t)NB * NO + idx] = (mv > T) ? 1.0f : 0.0f;
      }
    }
  }
}

// ---------------- fallback: round-4 fused kernel (known-PASS) --------------
__global__ __launch_bounds__(256) void snn_fused(
    const float* __restrict__ prev, const float* __restrict__ Wf,
    const float* __restrict__ own_mems, const float* __restrict__ own_spikes,
    const float* __restrict__ tau, float* __restrict__ out) {
  __shared__ __align__(16) unsigned short sA[128 * 32];
  __shared__ __align__(16) unsigned short sH[128 * 32];
  __shared__ __align__(16) unsigned short sL[128 * 32];
  const int tid = threadIdx.x;
  const int lane = tid & 63;
  const int wave = tid >> 6;
  const int wm = wave >> 1, wn = wave & 1;
  const int bn = blockIdx.x, bm = blockIdx.y;
  const int srow = tid >> 1;
  const int scol = (tid & 1) * 16;
  const float* gA = prev + (size_t)(bm * 128 + srow) * NK + scol;
  const float* gW = Wf + (size_t)(bn * 128 + srow) * NK + scol;
  const int sb = srow * 32 + scol;
  f32x4 acc[4][4];
#pragma unroll
  for (int i = 0; i < 4; ++i)
#pragma unroll
    for (int j = 0; j < 4; ++j) acc[i][j] = (f32x4){0.f, 0.f, 0.f, 0.f};
  const int fr = lane & 15;
  const int fq = lane >> 4;
  const int fk = fq * 8;
  for (int kt = 0; kt < NK / 32; ++kt) {
    const int ko = kt * 32;
    float av[16], wv[16];
    *(float4*)&av[0]  = *(const float4*)(gA + ko);
    *(float4*)&av[4]  = *(const float4*)(gA + ko + 4);
    *(float4*)&av[8]  = *(const float4*)(gA + ko + 8);
    *(float4*)&av[12] = *(const float4*)(gA + ko + 12);
    *(float4*)&wv[0]  = *(const float4*)(gW + ko);
    *(float4*)&wv[4]  = *(const float4*)(gW + ko + 4);
    *(float4*)&wv[8]  = *(const float4*)(gW + ko + 8);
    *(float4*)&wv[12] = *(const float4*)(gW + ko + 12);
    s16x8 va0, va1, vh0, vh1, vl0, vl1;
#pragma unroll
    for (int j = 0; j < 8; ++j) {
      va0[j] = (short)f2bf_rne(av[j]);
      va1[j] = (short)f2bf_rne(av[j + 8]);
      const unsigned short h0 = f2bf_rne(wv[j]);
      vh0[j] = (short)h0;
      vl0[j] = (short)f2bf_rne(wv[j] - bf2f(h0));
      const unsigned short h1 = f2bf_rne(wv[j + 8]);
      vh1[j] = (short)h1;
      vl1[j] = (short)f2bf_rne(wv[j + 8] - bf2f(h1));
    }
    __syncthreads();
    *(s16x8*)&sA[sb] = va0; *(s16x8*)&sA[sb + 8] = va1;
    *(s16x8*)&sH[sb] = vh0; *(s16x8*)&sH[sb + 8] = vh1;
    *(s16x8*)&sL[sb] = vl0; *(s16x8*)&sL[sb + 8] = vl1;
    __syncthreads();
    s16x8 af[4], bh[4], bl[4];
#pragma unroll
    for (int mi = 0; mi < 4; ++mi)
      af[mi] = *(const s16x8*)&sA[(wm * 64 + mi * 16 + fr) * 32 + fk];
#pragma unroll
    for (int ni = 0; ni < 4; ++ni) {
      bh[ni] = *(const s16x8*)&sH[(wn * 64 + ni * 16 + fr) * 32 + fk];
      bl[ni] = *(const s16x8*)&sL[(wn * 64 + ni * 16 + fr) * 32 + fk];
    }
#pragma unroll
    for (int mi = 0; mi < 4; ++mi)
#pragma unroll
      for (int ni = 0; ni < 4; ++ni) {
        acc[mi][ni] = __builtin_amdgcn_mfma_f32_16x16x32_bf16(af[mi], bh[ni], acc[mi][ni], 0, 0, 0);
        acc[mi][ni] = __builtin_amdgcn_mfma_f32_16x16x32_bf16(af[mi], bl[ni], acc[mi][ni], 0, 0, 0);
      }
  }
  unsigned long long fm = 0ull;
#pragma unroll
  for (int ni = 0; ni < 4; ++ni) {
    const int gc = bn * 128 + wn * 64 + ni * 16 + fr;
    const float alpha = 1.0f / (1.0f + expf(-tau[gc]));
#pragma unroll
    for (int mi = 0; mi < 4; ++mi) {
#pragma unroll
      for (int j = 0; j < 4; ++j) {
        const int gr = bm * 128 + wm * 64 + mi * 16 + fq * 4 + j;
        const size_t idx = (size_t)gr * NO + gc;
        const float dec = own_mems[idx] * alpha * (1.0f - own_spikes[idx]);
        const float mem = acc[mi][ni][j] + dec;
        out[idx] = (mem < 0.3f) ? mem : 0.0f;
        out[(size_t)NB * NO + idx] = (mem > 0.3f) ? 1.0f : 0.0f;
        if (fabsf(mem - 0.3f) < 1e-3f)
          fm |= 1ull << (mi * 16 + ni * 4 + j);
      }
    }
  }
#pragma unroll 1
  for (int r = 0; r < 64; ++r) {
    unsigned long long m = __ballot((fm >> r) & 1ull);
    if (m == 0ull) continue;
    const int mi = r >> 4, ni = (r >> 2) & 3, j = r & 3;
    const int gr_r = bm * 128 + wm * 64 + mi * 16 + fq * 4 + j;
    const int gc_r = bn * 128 + wn * 64 + ni * 16 + fr;
    while (m) {
      const int l = (int)__ffsll(m) - 1;
      m &= m - 1ull;
      const int gr = __shfl(gr_r, l, 64);
      const int gc = __shfl(gc_r, l, 64);
      const float* ap = prev + (size_t)gr * NK;
      const float* wp = Wf + (size_t)gc * NK;
      double s0 = 0.0, s1 = 0.0;
#pragma unroll 2
      for (int jj = 0; jj < 64; jj += 2) {
        s0 += (double)ap[lane + jj * 64]       * (double)wp[lane + jj * 64];
        s1 += (double)ap[lane + (jj + 1) * 64] * (double)wp[lane + (jj + 1) * 64];
      }
      double sum = s0 + s1;
#pragma unroll
      for (int off = 1; off < 64; off <<= 1) sum += __shfl_xor(sum, off, 64);
      if (lane == 0) {
        const size_t idx = (size_t)gr * NO + gc;
        const double alpha = 1.0 / (1.0 + exp(-(double)tau[gc]));
        const double dec = (double)own_mems[idx] * alpha * (1.0 - (double)own_spikes[idx]);
        const double mv = dec + sum;
        const double T = 0.3 + DELTA;
        out[idx] = (mv < T) ? (float)mv : 0.0f;
        out[(size_t)NB * NO + idx] = (mv > T) ? 1.0f : 0.0f;
      }
    }
  }
}

extern "C" void kernel_launch(void* const* d_in, const int* in_sizes, int n_in,
                              void* d_out, int out_size, void* d_ws, size_t ws_size,
                              hipStream_t stream) {
  const float* prev_spikes = (const float*)d_in[0];
  const float* own_mems    = (const float*)d_in[1];
  const float* own_spikes  = (const float*)d_in[2];
  const float* W           = (const float*)d_in[3];
  const float* tau         = (const float*)d_in[4];
  float* out = (float*)d_out;

  const size_t aBytes = (size_t)NB * NK;       // 4 MB i8 blobs
  const size_t wBytes = (size_t)NO * NK * 2;   // 32 MB i8 blobs (q1|q0)
  if (ws_size >= aBytes + wBytes) {
    char* p = (char*)d_ws;
    signed char* A8t = (signed char*)p;
    signed char* W8t = (signed char*)(p + aBytes);
    cvtA8t_kernel<<<1024, 256, 0, stream>>>(prev_spikes, A8t);
    cvtW8t_kernel<<<2048, 256, 0, stream>>>(W, W8t);
    snn_gemm_w8<<<512, 512, 0, stream>>>(A8t, W8t, prev_spikes, W,
                                         own_mems, own_spikes, tau, out);
  } else {
    snn_fused<<<dim3(NO / 128, NB / 128), 256, 0, stream>>>(
        prev_spikes, W, own_mems, own_spikes, tau, out);
  }
}